// Round 4
// baseline (1310.750 us; speedup 1.0000x reference)
//
#include <hip/hip_runtime.h>

typedef unsigned short u16;
typedef __attribute__((ext_vector_type(8))) short short8;
typedef __attribute__((ext_vector_type(4))) float float4v;

#define HID 64
#define MOLD 9
#define BSH 8            // bucket covers 1<<BSH = 256 nodes
#define NBMAX 1024

__device__ __forceinline__ float bf2f(u16 u) {
    return __uint_as_float(((unsigned)u) << 16);
}
__device__ __forceinline__ u16 f2bf(float f) {
    unsigned x = __float_as_uint(f);
    unsigned r = (x + 0x7FFFu + ((x >> 16) & 1u)) >> 16;  // round-nearest-even
    return (u16)r;
}
__device__ __forceinline__ void unpack_add(uint4 r, float* a) {
    a[0] += __uint_as_float(r.x << 16); a[1] += __uint_as_float(r.x & 0xffff0000u);
    a[2] += __uint_as_float(r.y << 16); a[3] += __uint_as_float(r.y & 0xffff0000u);
    a[4] += __uint_as_float(r.z << 16); a[5] += __uint_as_float(r.z & 0xffff0000u);
    a[6] += __uint_as_float(r.w << 16); a[7] += __uint_as_float(r.w & 0xffff0000u);
}
__device__ __forceinline__ void unpack_set(uint4 r, float* a) {
    a[0] = __uint_as_float(r.x << 16); a[1] = __uint_as_float(r.x & 0xffff0000u);
    a[2] = __uint_as_float(r.y << 16); a[3] = __uint_as_float(r.y & 0xffff0000u);
    a[4] = __uint_as_float(r.z << 16); a[5] = __uint_as_float(r.z & 0xffff0000u);
    a[6] = __uint_as_float(r.w << 16); a[7] = __uint_as_float(r.w & 0xffff0000u);
}

// ---- dtype probe ----
__global__ void k_detect(const u16* __restrict__ p, int n, int* __restrict__ flag) {
    bool bad = false;
    for (int i = threadIdx.x; i < n; i += 256) {
        float v = bf2f(p[i]);
        if (!(v == v) || fabsf(v) > 1000.f) bad = true;
    }
    if (bad) atomicOr(flag, 1);
}

__device__ __forceinline__ void cvt_seg(const void* src, u16* dst, int n, int mode) {
    if (mode) {
        const float* s = (const float*)src;
        for (int i = threadIdx.x; i < n; i += 256) dst[i] = f2bf(s[i]);
    } else {
        const u16* s = (const u16*)src;
        for (int i = threadIdx.x; i < n; i += 256) dst[i] = s[i];
    }
}

__global__ void k_cvt_w(const void* W1, const void* b1, const void* W2, const void* b2,
                        const void* W3, const void* b3, const void* Wl, const void* bl,
                        const int* __restrict__ flag, u16* __restrict__ wbf) {
    int mode = *flag;
    cvt_seg(W1, wbf + 0,     MOLD * HID, mode);
    cvt_seg(b1, wbf + 576,   HID, mode);
    cvt_seg(W2, wbf + 640,   HID * HID, mode);
    cvt_seg(b2, wbf + 4736,  HID, mode);
    cvt_seg(W3, wbf + 4800,  HID * HID, mode);
    cvt_seg(b3, wbf + 8896,  HID, mode);
    cvt_seg(Wl, wbf + 8960,  2 * HID * HID, mode);
    cvt_seg(bl, wbf + 17152, HID, mode);
}

__global__ void k_cvt_x(const void* __restrict__ src, u16* __restrict__ dst, int n,
                        const int* __restrict__ flag) {
    int mode = *flag;
    int i = blockIdx.x * 256 + threadIdx.x;
    if (i >= n) return;
    dst[i] = mode ? f2bf(((const float*)src)[i]) : ((const u16*)src)[i];
}

// ==== bucketed CSR build ====
// p1: per-block LDS histogram of dst>>BSH, merge to global
#define P1_EPT 16
__global__ __launch_bounds__(256) void k_p1(const int* __restrict__ ei, int E, int nb,
                                            int* __restrict__ bcount) {
    __shared__ int h[NBMAX];
    int tid = threadIdx.x;
    for (int i = tid; i < nb; i += 256) h[i] = 0;
    __syncthreads();
    int base = blockIdx.x * 256 * P1_EPT;
#pragma unroll
    for (int k = 0; k < P1_EPT; k++) {
        int e = base + k * 256 + tid;
        if (e < E) atomicAdd(&h[ei[E + e] >> BSH], 1);
    }
    __syncthreads();
    for (int i = tid; i < nb; i += 256) {
        int c = h[i];
        if (c) atomicAdd(&bcount[i], c);
    }
}

// p2: exclusive scan of nb (<=1024) bucket counts; 512 threads, 2 elems each
__global__ __launch_bounds__(512) void k_p2(const int* __restrict__ bcount, int nb, int E,
                                            int* __restrict__ bstart, int* __restrict__ bcursor) {
    __shared__ int ps[512];
    int tid = threadIdx.x;
    int a = (2 * tid     < nb) ? bcount[2 * tid]     : 0;
    int b = (2 * tid + 1 < nb) ? bcount[2 * tid + 1] : 0;
    ps[tid] = a + b;
    __syncthreads();
    for (int off = 1; off < 512; off <<= 1) {
        int t = (tid >= off) ? ps[tid - off] : 0;
        __syncthreads();
        ps[tid] += t;
        __syncthreads();
    }
    int base = (tid > 0) ? ps[tid - 1] : 0;  // exclusive pair prefix
    if (2 * tid < nb)     { bstart[2 * tid] = base;     bcursor[2 * tid] = base; }
    if (2 * tid + 1 < nb) { bstart[2 * tid + 1] = base + a; bcursor[2 * tid + 1] = base + a; }
    if (tid == 0) bstart[nb] = E;
}

// p3: scatter edges into bucket-contiguous staging, packed src | (dst&255)<<24
__global__ __launch_bounds__(256) void k_p3(const int* __restrict__ ei, int E,
                                            int* __restrict__ bcursor,
                                            unsigned* __restrict__ staging) {
    int e = blockIdx.x * 256 + threadIdx.x;
    if (e >= E) return;
    int s = ei[e];
    int d = ei[E + e];
    int b = d >> BSH;
    int p = atomicAdd(&bcursor[b], 1);
    staging[p] = (unsigned)s | ((unsigned)(d & ((1 << BSH) - 1)) << 24);
}

// p4: per-bucket counting sort in LDS -> rowptr, dinv, col
__global__ __launch_bounds__(256) void k_p4(const unsigned* __restrict__ staging,
                                            const int* __restrict__ bstart, int nb, int N, int E,
                                            int* __restrict__ col, int* __restrict__ rowptr,
                                            float* __restrict__ dinv) {
    __shared__ int cnt[256];
    __shared__ int sc[256];
    __shared__ int cur[256];
    int b = blockIdx.x;
    int tid = threadIdx.x;
    int s0 = bstart[b], s1 = bstart[b + 1];
    cnt[tid] = 0;
    __syncthreads();
    for (int i = s0 + tid; i < s1; i += 256)
        atomicAdd(&cnt[staging[i] >> 24], 1);
    __syncthreads();
    int c = cnt[tid];
    sc[tid] = c;
    __syncthreads();
    for (int off = 1; off < 256; off <<= 1) {
        int t = (tid >= off) ? sc[tid - off] : 0;
        __syncthreads();
        sc[tid] += t;
        __syncthreads();
    }
    int ex = sc[tid] - c;  // exclusive within bucket
    int v = (b << BSH) + tid;
    if (v < N) {
        rowptr[v] = s0 + ex;
        dinv[v] = rsqrtf((float)(c + 1));  // +1 self-loop
    }
    if (b == nb - 1 && tid == 0) rowptr[N] = E;
    cur[tid] = s0 + ex;
    __syncthreads();
    for (int i = s0 + tid; i < s1; i += 256) {
        unsigned w = staging[i];
        int p = atomicAdd(&cur[w >> 24], 1);
        col[p] = (int)(w & 0xFFFFFF);
    }
}

// ---- layer-1 dense ----
__global__ void k_l1(const u16* __restrict__ x, const u16* __restrict__ wseg,
                     const float* __restrict__ dinv, int N, u16* __restrict__ y) {
    __shared__ float w[MOLD * HID];
    int tid = threadIdx.x;
    for (int i = tid; i < MOLD * HID; i += blockDim.x) w[i] = bf2f(wseg[i]);
    __syncthreads();
    int v = blockIdx.x * 4 + (tid >> 6);
    int f = tid & 63;
    if (v >= N) return;
    float acc = 0.f;
#pragma unroll
    for (int k = 0; k < MOLD; k++) acc += bf2f(x[v * MOLD + k]) * w[k * HID + f];
    y[v * HID + f] = f2bf(dinv[v] * acc);
}

// ---- gather core: h[8] (post-relu) for feats fg*8+j, valid on ALL lanes ----
__device__ __forceinline__ void gather_node(const u16* __restrict__ y,
                                            const int* __restrict__ rowptr,
                                            const int* __restrict__ col,
                                            float dv, const float* breg,
                                            int v, int eslot, int fg, float* hj) {
    float acc[8];
    if (eslot == 0) {
        uint4 r = ((const uint4*)(y + (size_t)v * HID))[fg];
        unpack_set(r, acc);
    } else {
#pragma unroll
        for (int j = 0; j < 8; j++) acc[j] = 0.f;
    }
    int s = rowptr[v], e = rowptr[v + 1];
    for (int i = s; i < e; i += 8) {
        int idx = i + eslot;
        if (idx < e) {
            int u = col[idx];
            uint4 r = ((const uint4*)(y + (size_t)u * HID))[fg];
            unpack_add(r, acc);
        }
    }
#pragma unroll
    for (int j = 0; j < 8; j++) acc[j] += __shfl_xor(acc[j], 8);
#pragma unroll
    for (int j = 0; j < 8; j++) acc[j] += __shfl_xor(acc[j], 16);
#pragma unroll
    for (int j = 0; j < 8; j++) acc[j] += __shfl_xor(acc[j], 32);
#pragma unroll
    for (int j = 0; j < 8; j++) hj[j] = fmaxf(dv * acc[j] + breg[j], 0.f);
}

__device__ __forceinline__ void load_bias(const u16* bseg, int fg, float* breg) {
    uint4 bv = ((const uint4*)bseg)[fg];
    unpack_set(bv, breg);
}

// ---- agg layers 1,2 ----
__global__ __launch_bounds__(256, 4) void k_agg(
        const u16* __restrict__ y, const int* __restrict__ rowptr,
        const int* __restrict__ col, const float* __restrict__ dinv,
        const u16* __restrict__ bseg, int N, u16* __restrict__ h) {
    int lane = threadIdx.x & 63;
    int eslot = lane >> 3, fg = lane & 7;
    int wid = (blockIdx.x * blockDim.x + threadIdx.x) >> 6;
    int nw = (gridDim.x * blockDim.x) >> 6;
    float breg[8];
    load_bias(bseg, fg, breg);
    int cpw = (N + nw - 1) / nw;
    int v0 = wid * cpw;
    int v1 = v0 + cpw; if (v1 > N) v1 = N;
    for (int v = v0; v < v1; ++v) {
        float hj[8];
        gather_node(y, rowptr, col, dinv[v], breg, v, eslot, fg, hj);
        if (eslot == 0) {
            uint4 o;
            o.x = (unsigned)f2bf(hj[0]) | ((unsigned)f2bf(hj[1]) << 16);
            o.y = (unsigned)f2bf(hj[2]) | ((unsigned)f2bf(hj[3]) << 16);
            o.z = (unsigned)f2bf(hj[4]) | ((unsigned)f2bf(hj[5]) << 16);
            o.w = (unsigned)f2bf(hj[6]) | ((unsigned)f2bf(hj[7]) << 16);
            ((uint4*)(h + (size_t)v * HID))[fg] = o;
        }
    }
}

// ---- agg layer 3 + fused pooling ----
__global__ __launch_bounds__(256, 4) void k_aggpool(
        const u16* __restrict__ y, const int* __restrict__ rowptr,
        const int* __restrict__ col, const float* __restrict__ dinv,
        const u16* __restrict__ bseg, const int* __restrict__ batch, int N,
        float* __restrict__ hsum, int* __restrict__ hmax, int* __restrict__ cnt) {
    int lane = threadIdx.x & 63;
    int eslot = lane >> 3, fg = lane & 7;
    int wid = (blockIdx.x * blockDim.x + threadIdx.x) >> 6;
    int nw = (gridDim.x * blockDim.x) >> 6;
    float breg[8];
    load_bias(bseg, fg, breg);
    int cpw = (N + nw - 1) / nw;
    int v0 = wid * cpw;
    int v1 = v0 + cpw; if (v1 > N) v1 = N;
    int gcur = -1, pcnt = 0;
    float psum[8], pmax[8];
#pragma unroll
    for (int j = 0; j < 8; j++) { psum[j] = 0.f; pmax[j] = 0.f; }
    for (int v = v0; v < v1; ++v) {
        float hj[8];
        gather_node(y, rowptr, col, dinv[v], breg, v, eslot, fg, hj);
        int g = batch[v];
        if (g != gcur) {
            if (gcur >= 0) {
                if (eslot == 0) {
#pragma unroll
                    for (int j = 0; j < 8; j++) {
                        atomicAdd(&hsum[gcur * HID + fg * 8 + j], psum[j]);
                        atomicMax(&hmax[gcur * HID + fg * 8 + j], __float_as_int(pmax[j]));
                    }
                }
                if (lane == 0) atomicAdd(&cnt[gcur], pcnt);
            }
#pragma unroll
            for (int j = 0; j < 8; j++) { psum[j] = 0.f; pmax[j] = 0.f; }
            pcnt = 0;
            gcur = g;
        }
        pcnt++;
#pragma unroll
        for (int j = 0; j < 8; j++) {
            psum[j] += hj[j];
            pmax[j] = fmaxf(pmax[j], hj[j]);
        }
    }
    if (gcur >= 0) {
        if (eslot == 0) {
#pragma unroll
            for (int j = 0; j < 8; j++) {
                atomicAdd(&hsum[gcur * HID + fg * 8 + j], psum[j]);
                atomicMax(&hmax[gcur * HID + fg * 8 + j], __float_as_int(pmax[j]));
            }
        }
        if (lane == 0) atomicAdd(&cnt[gcur], pcnt);
    }
}

// ---- MFMA 64x64 dense ----
__global__ __launch_bounds__(256, 4) void k_mm(
        const u16* __restrict__ h, const u16* __restrict__ W,
        const float* __restrict__ dinv, int N, u16* __restrict__ y) {
    int lane = threadIdx.x & 63;
    int q = lane >> 4, m = lane & 15;
    int wid = (blockIdx.x * blockDim.x + threadIdx.x) >> 6;
    int nw = (gridDim.x * blockDim.x) >> 6;
    short8 bfrag[4][2];
#pragma unroll
    for (int t = 0; t < 4; ++t)
#pragma unroll
        for (int kh = 0; kh < 2; ++kh) {
            short8 bv;
#pragma unroll
            for (int j = 0; j < 8; ++j)
                bv[j] = (short)W[(kh * 32 + q * 8 + j) * HID + t * 16 + m];
            bfrag[t][kh] = bv;
        }
    const float4v zero = {0.f, 0.f, 0.f, 0.f};
    int ntiles = (N + 15) >> 4;
    for (int tile = wid; tile < ntiles; tile += nw) {
        int base = tile * 16;
        int row = base + m;
        short8 a0 = {0, 0, 0, 0, 0, 0, 0, 0}, a1 = a0;
        if (row < N) {
            uint4 r0 = *(const uint4*)(h + (size_t)row * HID + q * 8);
            uint4 r1 = *(const uint4*)(h + (size_t)row * HID + 32 + q * 8);
            a0 = __builtin_bit_cast(short8, r0);
            a1 = __builtin_bit_cast(short8, r1);
        }
        float4v c[4];
#pragma unroll
        for (int t = 0; t < 4; ++t) c[t] = zero;
#pragma unroll
        for (int t = 0; t < 4; ++t) {
            c[t] = __builtin_amdgcn_mfma_f32_16x16x32_bf16(a0, bfrag[t][0], c[t], 0, 0, 0);
            c[t] = __builtin_amdgcn_mfma_f32_16x16x32_bf16(a1, bfrag[t][1], c[t], 0, 0, 0);
        }
#pragma unroll
        for (int r = 0; r < 4; ++r) {
            int node = base + q * 4 + r;
            if (node < N) {
                float dv = dinv[node];
#pragma unroll
                for (int t = 0; t < 4; ++t)
                    y[(size_t)node * HID + t * 16 + m] = f2bf(c[t][r] * dv);
            }
        }
    }
}

// ---- final linear ----
__global__ void k_final(const float* __restrict__ hsum, const int* __restrict__ hmaxi,
                        const int* __restrict__ cnt, const u16* __restrict__ wlseg,
                        const u16* __restrict__ blseg, const int* __restrict__ flag,
                        int G, void* __restrict__ out) {
    __shared__ float w[2 * HID * HID];
    int tid = threadIdx.x;
    for (int i = tid; i < 2 * HID * HID; i += blockDim.x) w[i] = bf2f(wlseg[i]);
    __syncthreads();
    int g = blockIdx.x * 4 + (tid >> 6);
    int f = tid & 63;
    if (g >= G) return;
    float inv = 1.f / fmaxf((float)cnt[g], 1.f);
    float acc = bf2f(blseg[f]);
#pragma unroll 8
    for (int k = 0; k < HID; k++) acc += (hsum[g * HID + k] * inv) * w[k * HID + f];
#pragma unroll 8
    for (int k = 0; k < HID; k++) acc += __int_as_float(hmaxi[g * HID + k]) * w[(HID + k) * HID + f];
    int mode = *flag;
    if (mode) ((float*)out)[g * HID + f] = acc;
    else      ((u16*)out)[g * HID + f] = f2bf(acc);
}

extern "C" void kernel_launch(void* const* d_in, const int* in_sizes, int n_in,
                              void* d_out, int out_size, void* d_ws, size_t ws_size,
                              hipStream_t stream) {
    const void* x  = d_in[0];
    const int*  ei = (const int*)d_in[1];
    const int*  batch = (const int*)d_in[3];

    const int NX = in_sizes[0];
    const int N  = NX / MOLD;
    const int E  = in_sizes[1] / 2;
    const int G  = out_size / HID;
    const int nb = (N + (1 << BSH) - 1) >> BSH;   // buckets of 256 nodes

    char* p = (char*)d_ws;
    auto alloc = [&](size_t bytes) -> char* {
        char* r = p;
        p += (bytes + 255) & ~(size_t)255;
        return r;
    };
    int*   flag    = (int*)alloc(256);
    int*   rowptr  = (int*)alloc((size_t)(N + 1) * 4);
    float* dinv    = (float*)alloc((size_t)N * 4);
    int*   bcount  = (int*)alloc((size_t)nb * 4);
    int*   bstart  = (int*)alloc((size_t)(nb + 1) * 4);
    int*   bcursor = (int*)alloc((size_t)nb * 4);
    u16*   wbf     = (u16*)alloc((size_t)17216 * 2);
    int*   colb    = (int*)alloc((size_t)E * 4);
    // hbuf region (25.6 MB) reused 3x sequentially: staging -> xbf -> hbf
    size_t hb = (size_t)N * HID * 2;
    size_t sb = (size_t)E * 4;
    size_t xb = (size_t)NX * 2;
    size_t ub = hb > sb ? hb : sb; if (xb > ub) ub = xb;
    char* hbuf = alloc(ub);
    unsigned* staging = (unsigned*)hbuf;
    u16*      xbf     = (u16*)hbuf;
    u16*      hbf     = (u16*)hbuf;
    u16*   ybf  = (u16*)alloc((size_t)N * HID * 2);
    float* hsum = (float*)alloc((size_t)G * HID * 4);
    int*   hmax = (int*)alloc((size_t)G * HID * 4);
    int*   cnt  = (int*)alloc((size_t)G * 4);

    hipMemsetAsync(flag, 0, 256, stream);
    hipMemsetAsync(bcount, 0, (size_t)nb * 4, stream);
    hipMemsetAsync(hsum, 0, (size_t)G * HID * 4, stream);
    hipMemsetAsync(hmax, 0, (size_t)G * HID * 4, stream);
    hipMemsetAsync(cnt, 0, (size_t)G * 4, stream);

    k_detect<<<1, 256, 0, stream>>>((const u16*)x, 8192, flag);
    k_cvt_w<<<1, 256, 0, stream>>>(d_in[4], d_in[5], d_in[6], d_in[7],
                                   d_in[8], d_in[9], d_in[10], d_in[11], flag, wbf);

    // CSR build (bucketed)
    k_p1<<<(E + 256 * P1_EPT - 1) / (256 * P1_EPT), 256, 0, stream>>>(ei, E, nb, bcount);
    k_p2<<<1, 512, 0, stream>>>(bcount, nb, E, bstart, bcursor);
    k_p3<<<(E + 255) / 256, 256, 0, stream>>>(ei, E, bcursor, staging);
    k_p4<<<nb, 256, 0, stream>>>(staging, bstart, nb, N, E, colb, rowptr, dinv);

    // layer 1 dense (xbf aliases staging region — staging dead after p4)
    k_cvt_x<<<(NX + 255) / 256, 256, 0, stream>>>(x, xbf, NX, flag);
    k_l1<<<(N + 3) / 4, 256, 0, stream>>>(xbf, wbf + 0, dinv, N, ybf);

    k_agg<<<2048, 256, 0, stream>>>(ybf, rowptr, colb, dinv, wbf + 576, N, hbf);
    k_mm<<<1024, 256, 0, stream>>>(hbf, wbf + 640, dinv, N, ybf);
    k_agg<<<2048, 256, 0, stream>>>(ybf, rowptr, colb, dinv, wbf + 4736, N, hbf);
    k_mm<<<1024, 256, 0, stream>>>(hbf, wbf + 4800, dinv, N, ybf);
    k_aggpool<<<2048, 256, 0, stream>>>(ybf, rowptr, colb, dinv, wbf + 8896, batch, N,
                                        hsum, hmax, cnt);

    k_final<<<(G + 3) / 4, 256, 0, stream>>>(hsum, hmax, cnt, wbf + 8960, wbf + 17152,
                                             flag, G, d_out);
}

// Round 5
// 692.443 us; speedup vs baseline: 1.8929x; 1.8929x over previous
//
#include <hip/hip_runtime.h>

typedef unsigned short u16;
typedef __attribute__((ext_vector_type(8))) short short8;
typedef __attribute__((ext_vector_type(4))) float float4v;

#define HID 64
#define MOLD 9
#define BSH 10           // bucket covers 1<<BSH = 1024 nodes
#define NBM 256          // max buckets (supports N <= 262144; also src packs in 18 bits)
#define NBLK 256         // partition blocks

__device__ __forceinline__ float bf2f(u16 u) {
    return __uint_as_float(((unsigned)u) << 16);
}
__device__ __forceinline__ u16 f2bf(float f) {
    unsigned x = __float_as_uint(f);
    unsigned r = (x + 0x7FFFu + ((x >> 16) & 1u)) >> 16;  // round-nearest-even
    return (u16)r;
}
__device__ __forceinline__ void unpack_add(uint4 r, float* a) {
    a[0] += __uint_as_float(r.x << 16); a[1] += __uint_as_float(r.x & 0xffff0000u);
    a[2] += __uint_as_float(r.y << 16); a[3] += __uint_as_float(r.y & 0xffff0000u);
    a[4] += __uint_as_float(r.z << 16); a[5] += __uint_as_float(r.z & 0xffff0000u);
    a[6] += __uint_as_float(r.w << 16); a[7] += __uint_as_float(r.w & 0xffff0000u);
}
__device__ __forceinline__ void unpack_set(uint4 r, float* a) {
    a[0] = __uint_as_float(r.x << 16); a[1] = __uint_as_float(r.x & 0xffff0000u);
    a[2] = __uint_as_float(r.y << 16); a[3] = __uint_as_float(r.y & 0xffff0000u);
    a[4] = __uint_as_float(r.z << 16); a[5] = __uint_as_float(r.z & 0xffff0000u);
    a[6] = __uint_as_float(r.w << 16); a[7] = __uint_as_float(r.w & 0xffff0000u);
}

// ---- dtype probe ----
__global__ void k_detect(const u16* __restrict__ p, int n, int* __restrict__ flag) {
    bool bad = false;
    for (int i = threadIdx.x; i < n; i += 256) {
        float v = bf2f(p[i]);
        if (!(v == v) || fabsf(v) > 1000.f) bad = true;
    }
    if (bad) atomicOr(flag, 1);
}

__device__ __forceinline__ void cvt_seg(const void* src, u16* dst, int n, int mode) {
    if (mode) {
        const float* s = (const float*)src;
        for (int i = threadIdx.x; i < n; i += 256) dst[i] = f2bf(s[i]);
    } else {
        const u16* s = (const u16*)src;
        for (int i = threadIdx.x; i < n; i += 256) dst[i] = s[i];
    }
}

__global__ void k_cvt_w(const void* W1, const void* b1, const void* W2, const void* b2,
                        const void* W3, const void* b3, const void* Wl, const void* bl,
                        const int* __restrict__ flag, u16* __restrict__ wbf) {
    int mode = *flag;
    cvt_seg(W1, wbf + 0,     MOLD * HID, mode);
    cvt_seg(b1, wbf + 576,   HID, mode);
    cvt_seg(W2, wbf + 640,   HID * HID, mode);
    cvt_seg(b2, wbf + 4736,  HID, mode);
    cvt_seg(W3, wbf + 4800,  HID * HID, mode);
    cvt_seg(b3, wbf + 8896,  HID, mode);
    cvt_seg(Wl, wbf + 8960,  2 * HID * HID, mode);
    cvt_seg(bl, wbf + 17152, HID, mode);
}

__global__ void k_cvt_x(const void* __restrict__ src, u16* __restrict__ dst, int n,
                        const int* __restrict__ flag) {
    int mode = *flag;
    int i = blockIdx.x * 256 + threadIdx.x;
    if (i >= n) return;
    dst[i] = mode ? f2bf(((const float*)src)[i]) : ((const u16*)src)[i];
}

// ==== atomic-free two-level radix CSR build ====
// k_hist: per-block LDS histogram of dst buckets -> cntmat[b*NBLK + k]
__global__ __launch_bounds__(256) void k_hist(const int* __restrict__ ei, int E, int nb,
                                              int chunk, int* __restrict__ cntmat) {
    __shared__ int h[NBM];
    int tid = threadIdx.x, k = blockIdx.x;
    for (int i = tid; i < nb; i += 256) h[i] = 0;
    __syncthreads();
    int e0 = k * chunk, e1 = e0 + chunk; if (e1 > E) e1 = E;
    for (int e = e0 + tid; e < e1; e += 256)
        atomicAdd(&h[ei[E + e] >> BSH], 1);
    __syncthreads();
    for (int b = tid; b < nb; b += 256) cntmat[b * NBLK + k] = h[b];
}

// k_scanmat: in-place exclusive scan over nb*NBLK counts (bucket-major) -> offsets
__global__ __launch_bounds__(1024) void k_scanmat(int* __restrict__ cntmat, int total) {
    __shared__ int ps[1024];
    int tid = threadIdx.x;
    int chunk = (total + 1023) >> 10;
    int i0 = tid * chunk, i1 = i0 + chunk; if (i1 > total) i1 = total;
    int sum = 0;
    for (int i = i0; i < i1; i++) sum += cntmat[i];
    ps[tid] = sum;
    __syncthreads();
    for (int off = 1; off < 1024; off <<= 1) {
        int t = (tid >= off) ? ps[tid - off] : 0;
        __syncthreads();
        ps[tid] += t;
        __syncthreads();
    }
    int run = ps[tid] - sum;  // exclusive prefix of this thread's range
    for (int i = i0; i < i1; i++) { int c = cntmat[i]; cntmat[i] = run; run += c; }
}

// k_scatter: private per-(block,bucket) windows, LDS cursors only
__global__ __launch_bounds__(256) void k_scatter(const int* __restrict__ ei, int E, int nb,
                                                 int chunk, const int* __restrict__ offmat,
                                                 unsigned* __restrict__ staging) {
    __shared__ int cur[NBM];
    int tid = threadIdx.x, k = blockIdx.x;
    for (int b = tid; b < nb; b += 256) cur[b] = offmat[b * NBLK + k];
    __syncthreads();
    int e0 = k * chunk, e1 = e0 + chunk; if (e1 > E) e1 = E;
    for (int e = e0 + tid; e < e1; e += 256) {
        int s = ei[e];
        int d = ei[E + e];
        int b = d >> BSH;
        int p = atomicAdd(&cur[b], 1);
        staging[p] = (unsigned)s | ((unsigned)(d & ((1 << BSH) - 1)) << 18);
    }
}

// k_p4: per-bucket counting sort (1024 LDS counters) -> rowptr, dinv, col
__global__ __launch_bounds__(256) void k_p4(const unsigned* __restrict__ staging,
                                            const int* __restrict__ offmat, int nb, int N, int E,
                                            int* __restrict__ col, int* __restrict__ rowptr,
                                            float* __restrict__ dinv) {
    __shared__ int cnt[1 << BSH];
    __shared__ int cur[1 << BSH];
    __shared__ int ps[256];
    int b = blockIdx.x, tid = threadIdx.x;
    int s0 = offmat[b * NBLK];
    int s1 = (b == nb - 1) ? E : offmat[(b + 1) * NBLK];
    for (int i = tid; i < (1 << BSH); i += 256) cnt[i] = 0;
    __syncthreads();
    for (int i = s0 + tid; i < s1; i += 256)
        atomicAdd(&cnt[staging[i] >> 18], 1);
    __syncthreads();
    // scan 1024 counters, 4 per thread
    int base4 = tid * 4;
    int c0 = cnt[base4], c1 = cnt[base4 + 1], c2 = cnt[base4 + 2], c3 = cnt[base4 + 3];
    int tsum = c0 + c1 + c2 + c3;
    ps[tid] = tsum;
    __syncthreads();
    for (int off = 1; off < 256; off <<= 1) {
        int t = (tid >= off) ? ps[tid - off] : 0;
        __syncthreads();
        ps[tid] += t;
        __syncthreads();
    }
    int ex = ps[tid] - tsum;
    int o0 = s0 + ex, o1 = o0 + c0, o2 = o1 + c1, o3 = o2 + c2;
    cur[base4] = o0; cur[base4 + 1] = o1; cur[base4 + 2] = o2; cur[base4 + 3] = o3;
    int v = (b << BSH) + base4;
    if (v < N)     { rowptr[v] = o0;     dinv[v] = rsqrtf((float)(c0 + 1)); }
    if (v + 1 < N) { rowptr[v + 1] = o1; dinv[v + 1] = rsqrtf((float)(c1 + 1)); }
    if (v + 2 < N) { rowptr[v + 2] = o2; dinv[v + 2] = rsqrtf((float)(c2 + 1)); }
    if (v + 3 < N) { rowptr[v + 3] = o3; dinv[v + 3] = rsqrtf((float)(c3 + 1)); }
    if (b == nb - 1 && tid == 0) rowptr[N] = E;
    __syncthreads();
    for (int i = s0 + tid; i < s1; i += 256) {
        unsigned w = staging[i];
        int p = atomicAdd(&cur[w >> 18], 1);
        col[p] = (int)(w & 0x3FFFF);
    }
}

// ---- layer-1 dense ----
__global__ void k_l1(const u16* __restrict__ x, const u16* __restrict__ wseg,
                     const float* __restrict__ dinv, int N, u16* __restrict__ y) {
    __shared__ float w[MOLD * HID];
    int tid = threadIdx.x;
    for (int i = tid; i < MOLD * HID; i += blockDim.x) w[i] = bf2f(wseg[i]);
    __syncthreads();
    int v = blockIdx.x * 4 + (tid >> 6);
    int f = tid & 63;
    if (v >= N) return;
    float acc = 0.f;
#pragma unroll
    for (int k = 0; k < MOLD; k++) acc += bf2f(x[v * MOLD + k]) * w[k * HID + f];
    y[v * HID + f] = f2bf(dinv[v] * acc);
}

// ---- gather core: h[8] (post-relu) for feats fg*8+j, valid on ALL lanes ----
__device__ __forceinline__ void gather_node(const u16* __restrict__ y,
                                            const int* __restrict__ rowptr,
                                            const int* __restrict__ col,
                                            float dv, const float* breg,
                                            int v, int eslot, int fg, float* hj) {
    float acc[8];
    if (eslot == 0) {
        uint4 r = ((const uint4*)(y + (size_t)v * HID))[fg];
        unpack_set(r, acc);
    } else {
#pragma unroll
        for (int j = 0; j < 8; j++) acc[j] = 0.f;
    }
    int s = rowptr[v], e = rowptr[v + 1];
    for (int i = s; i < e; i += 8) {
        int idx = i + eslot;
        if (idx < e) {
            int u = col[idx];
            uint4 r = ((const uint4*)(y + (size_t)u * HID))[fg];
            unpack_add(r, acc);
        }
    }
#pragma unroll
    for (int j = 0; j < 8; j++) acc[j] += __shfl_xor(acc[j], 8);
#pragma unroll
    for (int j = 0; j < 8; j++) acc[j] += __shfl_xor(acc[j], 16);
#pragma unroll
    for (int j = 0; j < 8; j++) acc[j] += __shfl_xor(acc[j], 32);
#pragma unroll
    for (int j = 0; j < 8; j++) hj[j] = fmaxf(dv * acc[j] + breg[j], 0.f);
}

__device__ __forceinline__ void load_bias(const u16* bseg, int fg, float* breg) {
    uint4 bv = ((const uint4*)bseg)[fg];
    unpack_set(bv, breg);
}

// ---- agg layers 1,2 ----
__global__ __launch_bounds__(256, 4) void k_agg(
        const u16* __restrict__ y, const int* __restrict__ rowptr,
        const int* __restrict__ col, const float* __restrict__ dinv,
        const u16* __restrict__ bseg, int N, u16* __restrict__ h) {
    int lane = threadIdx.x & 63;
    int eslot = lane >> 3, fg = lane & 7;
    int wid = (blockIdx.x * blockDim.x + threadIdx.x) >> 6;
    int nw = (gridDim.x * blockDim.x) >> 6;
    float breg[8];
    load_bias(bseg, fg, breg);
    int cpw = (N + nw - 1) / nw;
    int v0 = wid * cpw;
    int v1 = v0 + cpw; if (v1 > N) v1 = N;
    for (int v = v0; v < v1; ++v) {
        float hj[8];
        gather_node(y, rowptr, col, dinv[v], breg, v, eslot, fg, hj);
        if (eslot == 0) {
            uint4 o;
            o.x = (unsigned)f2bf(hj[0]) | ((unsigned)f2bf(hj[1]) << 16);
            o.y = (unsigned)f2bf(hj[2]) | ((unsigned)f2bf(hj[3]) << 16);
            o.z = (unsigned)f2bf(hj[4]) | ((unsigned)f2bf(hj[5]) << 16);
            o.w = (unsigned)f2bf(hj[6]) | ((unsigned)f2bf(hj[7]) << 16);
            ((uint4*)(h + (size_t)v * HID))[fg] = o;
        }
    }
}

// ---- agg layer 3 + fused pooling ----
__global__ __launch_bounds__(256, 4) void k_aggpool(
        const u16* __restrict__ y, const int* __restrict__ rowptr,
        const int* __restrict__ col, const float* __restrict__ dinv,
        const u16* __restrict__ bseg, const int* __restrict__ batch, int N,
        float* __restrict__ hsum, int* __restrict__ hmax, int* __restrict__ cnt) {
    int lane = threadIdx.x & 63;
    int eslot = lane >> 3, fg = lane & 7;
    int wid = (blockIdx.x * blockDim.x + threadIdx.x) >> 6;
    int nw = (gridDim.x * blockDim.x) >> 6;
    float breg[8];
    load_bias(bseg, fg, breg);
    int cpw = (N + nw - 1) / nw;
    int v0 = wid * cpw;
    int v1 = v0 + cpw; if (v1 > N) v1 = N;
    int gcur = -1, pcnt = 0;
    float psum[8], pmax[8];
#pragma unroll
    for (int j = 0; j < 8; j++) { psum[j] = 0.f; pmax[j] = 0.f; }
    for (int v = v0; v < v1; ++v) {
        float hj[8];
        gather_node(y, rowptr, col, dinv[v], breg, v, eslot, fg, hj);
        int g = batch[v];
        if (g != gcur) {
            if (gcur >= 0) {
                if (eslot == 0) {
#pragma unroll
                    for (int j = 0; j < 8; j++) {
                        atomicAdd(&hsum[gcur * HID + fg * 8 + j], psum[j]);
                        atomicMax(&hmax[gcur * HID + fg * 8 + j], __float_as_int(pmax[j]));
                    }
                }
                if (lane == 0) atomicAdd(&cnt[gcur], pcnt);
            }
#pragma unroll
            for (int j = 0; j < 8; j++) { psum[j] = 0.f; pmax[j] = 0.f; }
            pcnt = 0;
            gcur = g;
        }
        pcnt++;
#pragma unroll
        for (int j = 0; j < 8; j++) {
            psum[j] += hj[j];
            pmax[j] = fmaxf(pmax[j], hj[j]);
        }
    }
    if (gcur >= 0) {
        if (eslot == 0) {
#pragma unroll
            for (int j = 0; j < 8; j++) {
                atomicAdd(&hsum[gcur * HID + fg * 8 + j], psum[j]);
                atomicMax(&hmax[gcur * HID + fg * 8 + j], __float_as_int(pmax[j]));
            }
        }
        if (lane == 0) atomicAdd(&cnt[gcur], pcnt);
    }
}

// ---- MFMA 64x64 dense ----
__global__ __launch_bounds__(256, 4) void k_mm(
        const u16* __restrict__ h, const u16* __restrict__ W,
        const float* __restrict__ dinv, int N, u16* __restrict__ y) {
    int lane = threadIdx.x & 63;
    int q = lane >> 4, m = lane & 15;
    int wid = (blockIdx.x * blockDim.x + threadIdx.x) >> 6;
    int nw = (gridDim.x * blockDim.x) >> 6;
    short8 bfrag[4][2];
#pragma unroll
    for (int t = 0; t < 4; ++t)
#pragma unroll
        for (int kh = 0; kh < 2; ++kh) {
            short8 bv;
#pragma unroll
            for (int j = 0; j < 8; ++j)
                bv[j] = (short)W[(kh * 32 + q * 8 + j) * HID + t * 16 + m];
            bfrag[t][kh] = bv;
        }
    const float4v zero = {0.f, 0.f, 0.f, 0.f};
    int ntiles = (N + 15) >> 4;
    for (int tile = wid; tile < ntiles; tile += nw) {
        int base = tile * 16;
        int row = base + m;
        short8 a0 = {0, 0, 0, 0, 0, 0, 0, 0}, a1 = a0;
        if (row < N) {
            uint4 r0 = *(const uint4*)(h + (size_t)row * HID + q * 8);
            uint4 r1 = *(const uint4*)(h + (size_t)row * HID + 32 + q * 8);
            a0 = __builtin_bit_cast(short8, r0);
            a1 = __builtin_bit_cast(short8, r1);
        }
        float4v c[4];
#pragma unroll
        for (int t = 0; t < 4; ++t) c[t] = zero;
#pragma unroll
        for (int t = 0; t < 4; ++t) {
            c[t] = __builtin_amdgcn_mfma_f32_16x16x32_bf16(a0, bfrag[t][0], c[t], 0, 0, 0);
            c[t] = __builtin_amdgcn_mfma_f32_16x16x32_bf16(a1, bfrag[t][1], c[t], 0, 0, 0);
        }
#pragma unroll
        for (int r = 0; r < 4; ++r) {
            int node = base + q * 4 + r;
            if (node < N) {
                float dv = dinv[node];
#pragma unroll
                for (int t = 0; t < 4; ++t)
                    y[(size_t)node * HID + t * 16 + m] = f2bf(c[t][r] * dv);
            }
        }
    }
}

// ---- final linear ----
__global__ void k_final(const float* __restrict__ hsum, const int* __restrict__ hmaxi,
                        const int* __restrict__ cnt, const u16* __restrict__ wlseg,
                        const u16* __restrict__ blseg, const int* __restrict__ flag,
                        int G, void* __restrict__ out) {
    __shared__ float w[2 * HID * HID];
    int tid = threadIdx.x;
    for (int i = tid; i < 2 * HID * HID; i += blockDim.x) w[i] = bf2f(wlseg[i]);
    __syncthreads();
    int g = blockIdx.x * 4 + (tid >> 6);
    int f = tid & 63;
    if (g >= G) return;
    float inv = 1.f / fmaxf((float)cnt[g], 1.f);
    float acc = bf2f(blseg[f]);
#pragma unroll 8
    for (int k = 0; k < HID; k++) acc += (hsum[g * HID + k] * inv) * w[k * HID + f];
#pragma unroll 8
    for (int k = 0; k < HID; k++) acc += __int_as_float(hmaxi[g * HID + k]) * w[(HID + k) * HID + f];
    int mode = *flag;
    if (mode) ((float*)out)[g * HID + f] = acc;
    else      ((u16*)out)[g * HID + f] = f2bf(acc);
}

extern "C" void kernel_launch(void* const* d_in, const int* in_sizes, int n_in,
                              void* d_out, int out_size, void* d_ws, size_t ws_size,
                              hipStream_t stream) {
    const void* x  = d_in[0];
    const int*  ei = (const int*)d_in[1];
    const int*  batch = (const int*)d_in[3];

    const int NX = in_sizes[0];
    const int N  = NX / MOLD;
    const int E  = in_sizes[1] / 2;
    const int G  = out_size / HID;
    const int nb = (N + (1 << BSH) - 1) >> BSH;   // buckets of 1024 nodes

    char* p = (char*)d_ws;
    auto alloc = [&](size_t bytes) -> char* {
        char* r = p;
        p += (bytes + 255) & ~(size_t)255;
        return r;
    };
    int*   flag    = (int*)alloc(256);
    int*   rowptr  = (int*)alloc((size_t)(N + 1) * 4);
    float* dinv    = (float*)alloc((size_t)N * 4);
    int*   cntmat  = (int*)alloc((size_t)nb * NBLK * 4);
    u16*   wbf     = (u16*)alloc((size_t)17216 * 2);
    int*   colb    = (int*)alloc((size_t)E * 4);
    // hbuf region reused sequentially: staging -> xbf -> hbf
    size_t hb = (size_t)N * HID * 2;
    size_t sb = (size_t)E * 4;
    size_t xb = (size_t)NX * 2;
    size_t ub = hb > sb ? hb : sb; if (xb > ub) ub = xb;
    char* hbuf = alloc(ub);
    unsigned* staging = (unsigned*)hbuf;
    u16*      xbf     = (u16*)hbuf;
    u16*      hbf     = (u16*)hbuf;
    u16*   ybf  = (u16*)alloc((size_t)N * HID * 2);
    float* hsum = (float*)alloc((size_t)G * HID * 4);
    int*   hmax = (int*)alloc((size_t)G * HID * 4);
    int*   cnt  = (int*)alloc((size_t)G * 4);

    hipMemsetAsync(flag, 0, 256, stream);
    hipMemsetAsync(hsum, 0, (size_t)G * HID * 4, stream);
    hipMemsetAsync(hmax, 0, (size_t)G * HID * 4, stream);
    hipMemsetAsync(cnt, 0, (size_t)G * 4, stream);

    k_detect<<<1, 256, 0, stream>>>((const u16*)x, 8192, flag);
    k_cvt_w<<<1, 256, 0, stream>>>(d_in[4], d_in[5], d_in[6], d_in[7],
                                   d_in[8], d_in[9], d_in[10], d_in[11], flag, wbf);

    // CSR build: atomic-free radix partition
    int chunk = (E + NBLK - 1) / NBLK;
    k_hist<<<NBLK, 256, 0, stream>>>(ei, E, nb, chunk, cntmat);
    k_scanmat<<<1, 1024, 0, stream>>>(cntmat, nb * NBLK);
    k_scatter<<<NBLK, 256, 0, stream>>>(ei, E, nb, chunk, cntmat, staging);
    k_p4<<<nb, 256, 0, stream>>>(staging, cntmat, nb, N, E, colb, rowptr, dinv);

    // layer 1 dense (xbf aliases staging region — staging dead after p4)
    k_cvt_x<<<(NX + 255) / 256, 256, 0, stream>>>(x, xbf, NX, flag);
    k_l1<<<(N + 3) / 4, 256, 0, stream>>>(xbf, wbf + 0, dinv, N, ybf);

    k_agg<<<2048, 256, 0, stream>>>(ybf, rowptr, colb, dinv, wbf + 576, N, hbf);
    k_mm<<<1024, 256, 0, stream>>>(hbf, wbf + 640, dinv, N, ybf);
    k_agg<<<2048, 256, 0, stream>>>(ybf, rowptr, colb, dinv, wbf + 4736, N, hbf);
    k_mm<<<1024, 256, 0, stream>>>(hbf, wbf + 4800, dinv, N, ybf);
    k_aggpool<<<2048, 256, 0, stream>>>(ybf, rowptr, colb, dinv, wbf + 8896, batch, N,
                                        hsum, hmax, cnt);

    k_final<<<(G + 3) / 4, 256, 0, stream>>>(hsum, hmax, cnt, wbf + 8960, wbf + 17152,
                                             flag, G, d_out);
}